// Round 5
// baseline (140.321 us; speedup 1.0000x reference)
//
#include <hip/hip_runtime.h>
#include <float.h>

// PytorchTokenFeaturer: per segment s (65536 segments, ~16 contiguous rows each,
// D=128 fp32): out[s] = concat(first_row, mean_rows, max_rows) -> [S, 384] fp32.
// Memory-bound: 512 MB read + 96 MB write.
//
// R5: persistent-style waves. 8192 waves total (one full machine residency),
// each wave owns 8 CONSECUTIVE segments = one contiguous ~64 KB read stream.
// All 9 segment boundaries loaded up-front (wave-uniform scalar loads), so the
// per-segment startup chain (dependent offset loads) is paid once per wave,
// not once per segment. Inner body = R3's burst loop (pipelining was neutral).

typedef float f32x4 __attribute__((ext_vector_type(4)));

constexpr int NSEG = 65536;
constexpr int NTOK = 1048576;
constexpr int D4   = 32;      // f32x4 per row (D=128)
constexpr int SPW  = 8;       // segments per wave

__global__ __launch_bounds__(256, 8) void token_feat_kernel(
    const f32x4* __restrict__ v4,
    const int*   __restrict__ offsets,
    f32x4*       __restrict__ out4)
{
    const int gid  = blockIdx.x * blockDim.x + threadIdx.x;
    const int wave = gid >> 6;
    const int lane = gid & 63;
    const int c    = lane & 31;      // column group (f32x4 index within row)
    const int h    = lane >> 5;      // row parity for this half-wave

    const int segBase = wave * SPW;  // wave-uniform
    if (segBase >= NSEG) return;

    // all boundaries for this wave's chunk, loaded once (uniform -> s_load)
    int offs[SPW + 1];
#pragma unroll
    for (int i = 0; i < SPW; ++i) offs[i] = offsets[segBase + i];
    offs[SPW] = (segBase + SPW < NSEG) ? offsets[segBase + SPW] : NTOK;

#pragma unroll 1
    for (int j = 0; j < SPW; ++j) {
        const int start = offs[j];
        const int L     = offs[j + 1] - start;
        const f32x4* __restrict__ base = v4 + (size_t)start * D4 + c;

        f32x4 sum   = (f32x4){0.f, 0.f, 0.f, 0.f};
        f32x4 mx    = (f32x4){-FLT_MAX, -FLT_MAX, -FLT_MAX, -FLT_MAX};
        f32x4 first = (f32x4){0.f, 0.f, 0.f, 0.f};

        int r0 = 0;
        // 8 rows per burst: 4 independent 1KB loads in flight
        for (; r0 + 8 <= L; r0 += 8) {
            const f32x4 w0 = base[(size_t)(r0 + 0 + h) * D4];
            const f32x4 w1 = base[(size_t)(r0 + 2 + h) * D4];
            const f32x4 w2 = base[(size_t)(r0 + 4 + h) * D4];
            const f32x4 w3 = base[(size_t)(r0 + 6 + h) * D4];
            if (r0 == 0) first = w0;     // h==0 lanes hold row 0
            sum += w0 + w1 + w2 + w3;
            mx.x = fmaxf(fmaxf(fmaxf(mx.x, w0.x), fmaxf(w1.x, w2.x)), w3.x);
            mx.y = fmaxf(fmaxf(fmaxf(mx.y, w0.y), fmaxf(w1.y, w2.y)), w3.y);
            mx.z = fmaxf(fmaxf(fmaxf(mx.z, w0.z), fmaxf(w1.z, w2.z)), w3.z);
            mx.w = fmaxf(fmaxf(fmaxf(mx.w, w0.w), fmaxf(w1.w, w2.w)), w3.w);
        }
        // tail: rows r0..L-1, this half-wave takes r0+h, r0+h+2, ...
        for (int r = r0 + h; r < L; r += 2) {
            const f32x4 w = base[(size_t)r * D4];
            if (r == 0) first = w;       // only when L < 8
            sum += w;
            mx.x = fmaxf(mx.x, w.x);  mx.y = fmaxf(mx.y, w.y);
            mx.z = fmaxf(mx.z, w.z);  mx.w = fmaxf(mx.w, w.w);
        }

        // combine the two half-waves (lane ^ 32)
        sum.x += __shfl_xor(sum.x, 32);
        sum.y += __shfl_xor(sum.y, 32);
        sum.z += __shfl_xor(sum.z, 32);
        sum.w += __shfl_xor(sum.w, 32);
        mx.x = fmaxf(mx.x, __shfl_xor(mx.x, 32));
        mx.y = fmaxf(mx.y, __shfl_xor(mx.y, 32));
        mx.z = fmaxf(mx.z, __shfl_xor(mx.z, 32));
        mx.w = fmaxf(mx.w, __shfl_xor(mx.w, 32));

        const float inv  = 1.0f / (float)L;
        const f32x4 mean = sum * inv;

        // out row = 96 f32x4: [0,32)=first, [32,64)=mean, [64,96)=max
        f32x4* __restrict__ o = out4 + (size_t)(segBase + j) * 96;
        if (lane < 32) {
            __builtin_nontemporal_store(first, o + c);
        }
        const f32x4 mm = (lane < 32) ? mean : mx;  // lanes>=32: 32+lane = 64+c
        __builtin_nontemporal_store(mm, o + 32 + lane);
    }
}

extern "C" void kernel_launch(void* const* d_in, const int* in_sizes, int n_in,
                              void* d_out, int out_size, void* d_ws, size_t ws_size,
                              hipStream_t stream) {
    const f32x4* values  = (const f32x4*)d_in[0];
    // d_in[1] = segment_ids: unused (segments contiguous; offsets determine them)
    const int*   offsets = (const int*)d_in[2];
    f32x4*       out     = (f32x4*)d_out;

    const int threads       = 256;                    // 4 waves/block
    const int wavesPerBlock = threads / 64;
    const int totalWaves    = NSEG / SPW;             // 8192 = one full residency
    const int blocks        = totalWaves / wavesPerBlock;   // 2048
    token_feat_kernel<<<blocks, threads, 0, stream>>>(values, offsets, out);
}

// Round 6
// 118.856 us; speedup vs baseline: 1.1806x; 1.1806x over previous
//
#include <hip/hip_runtime.h>
#include <float.h>

// PytorchTokenFeaturer: per segment s (65536 segments, ~16 contiguous rows each,
// D=128 fp32): out[s] = concat(first_row, mean_rows, max_rows) -> [S, 384] fp32.
// Memory-bound: 536.9 MB read + 100.7 MB write = 637.8 MB.
// Best measured: 119 us = 5.36 TB/s = 85% of copy-ubench (6.29 TB/s) — at the
// practical ceiling for real memory-bound kernels on MI355X (cf. RMSNorm 86%).
//
// One wave per segment (65536 waves, ~8 generations — smooths the ~9% per-wave
// work variance; persistent SPW=8 waves regressed 18% from straggler tail).
// f32x4 per lane: lane i covers col group c=(i&31), row parity h=(i>>5); each
// load instr = 1KB (2 full rows), 4 independent loads in flight per burst.
// Deeper pipelining (R4) measured neutral — per-wave MLP is not the limit.

typedef float f32x4 __attribute__((ext_vector_type(4)));

constexpr int NSEG = 65536;
constexpr int NTOK = 1048576;
constexpr int D4   = 32;   // f32x4 per row (D=128)

__global__ __launch_bounds__(256) void token_feat_kernel(
    const f32x4* __restrict__ v4,
    const int*   __restrict__ offsets,
    f32x4*       __restrict__ out4)
{
    const int gid  = blockIdx.x * blockDim.x + threadIdx.x;
    const int seg  = gid >> 6;          // one wave per segment
    const int lane = gid & 63;
    if (seg >= NSEG) return;

    const int start = offsets[seg];
    const int end   = (seg + 1 < NSEG) ? offsets[seg + 1] : NTOK;
    const int L     = end - start;

    const int c = lane & 31;            // column group (f32x4 index within row)
    const int h = lane >> 5;            // row parity for this half-wave

    const f32x4* __restrict__ base = v4 + (size_t)start * D4 + c;

    f32x4 sum   = (f32x4){0.f, 0.f, 0.f, 0.f};
    f32x4 mx    = (f32x4){-FLT_MAX, -FLT_MAX, -FLT_MAX, -FLT_MAX};
    f32x4 first = (f32x4){0.f, 0.f, 0.f, 0.f};

    int r0 = 0;
    // 8 rows per burst: 4 independent 1KB loads in flight
    for (; r0 + 8 <= L; r0 += 8) {
        const f32x4 w0 = base[(size_t)(r0 + 0 + h) * D4];
        const f32x4 w1 = base[(size_t)(r0 + 2 + h) * D4];
        const f32x4 w2 = base[(size_t)(r0 + 4 + h) * D4];
        const f32x4 w3 = base[(size_t)(r0 + 6 + h) * D4];
        if (r0 == 0) first = w0;        // h==0 lanes hold row 0
        sum += w0 + w1 + w2 + w3;
        mx.x = fmaxf(fmaxf(fmaxf(mx.x, w0.x), fmaxf(w1.x, w2.x)), w3.x);
        mx.y = fmaxf(fmaxf(fmaxf(mx.y, w0.y), fmaxf(w1.y, w2.y)), w3.y);
        mx.z = fmaxf(fmaxf(fmaxf(mx.z, w0.z), fmaxf(w1.z, w2.z)), w3.z);
        mx.w = fmaxf(fmaxf(fmaxf(mx.w, w0.w), fmaxf(w1.w, w2.w)), w3.w);
    }
    // tail: rows r0..L-1, this half-wave takes r0+h, r0+h+2, ...
    for (int r = r0 + h; r < L; r += 2) {
        const f32x4 w = base[(size_t)r * D4];
        if (r == 0) first = w;          // only when L < 8
        sum += w;
        mx.x = fmaxf(mx.x, w.x);  mx.y = fmaxf(mx.y, w.y);
        mx.z = fmaxf(mx.z, w.z);  mx.w = fmaxf(mx.w, w.w);
    }

    // combine the two half-waves (lane ^ 32)
    sum.x += __shfl_xor(sum.x, 32);
    sum.y += __shfl_xor(sum.y, 32);
    sum.z += __shfl_xor(sum.z, 32);
    sum.w += __shfl_xor(sum.w, 32);
    mx.x = fmaxf(mx.x, __shfl_xor(mx.x, 32));
    mx.y = fmaxf(mx.y, __shfl_xor(mx.y, 32));
    mx.z = fmaxf(mx.z, __shfl_xor(mx.z, 32));
    mx.w = fmaxf(mx.w, __shfl_xor(mx.w, 32));

    const float inv  = 1.0f / (float)L;
    const f32x4 mean = sum * inv;

    // out row = 96 f32x4: [0,32)=first, [32,64)=mean, [64,96)=max
    f32x4* __restrict__ o = out4 + (size_t)seg * 96;
    if (lane < 32) {
        __builtin_nontemporal_store(first, o + c);
    }
    const f32x4 mm = (lane < 32) ? mean : mx;   // lanes>=32: 32+lane = 64+c
    __builtin_nontemporal_store(mm, o + 32 + lane);
}

extern "C" void kernel_launch(void* const* d_in, const int* in_sizes, int n_in,
                              void* d_out, int out_size, void* d_ws, size_t ws_size,
                              hipStream_t stream) {
    const f32x4* values  = (const f32x4*)d_in[0];
    // d_in[1] = segment_ids: unused (segments contiguous; offsets determine them)
    const int*   offsets = (const int*)d_in[2];
    f32x4*       out     = (f32x4*)d_out;

    const int threads       = 256;               // 4 waves/block
    const int wavesPerBlock = threads / 64;
    const int blocks        = NSEG / wavesPerBlock;
    token_feat_kernel<<<blocks, threads, 0, stream>>>(values, offsets, out);
}